// Round 1
// baseline (1128.072 us; speedup 1.0000x reference)
//
#include <hip/hip_runtime.h>
#include <math.h>

// ---------------------------------------------------------------------------
// Problem constants (S=512, B=16, E=512, A=512, H=8, P=4, L=512)
//   hd=64, vd=32, KV=1024, S2=1535, in_out=1312
// Output layout (floats): out[4194304] | weights[67108864] | ck[4194304] | cv[2097152]
// Workspace (floats): q[4194304] | p[262144] | pos[49120] | attnout[2097152]
// ---------------------------------------------------------------------------

// Generic f32 GEMM-NT: C[M,N] = A[M,K] * B[N,K]^T (+bias). mode==1 routes the
// in_proj output columns to q_ws / ck / cv / p_ws (boundaries are tile-aligned).
__global__ __launch_bounds__(256)
void gemm_nt(const float* __restrict__ A, const float* __restrict__ B,
             const float* __restrict__ bias, int M, int N, int K,
             int mode, float* __restrict__ C, int ldc,
             float* __restrict__ q_ws, float* __restrict__ ck,
             float* __restrict__ cv, float* __restrict__ p_ws)
{
    __shared__ float As[16][68];   // transposed tiles, padded (bank-friendly)
    __shared__ float Bs[16][68];
    const int t  = threadIdx.x;
    const int m0 = blockIdx.y * 64, n0 = blockIdx.x * 64;
    const int lr = t >> 2;          // 0..63 tile row
    const int lc = (t & 3) * 4;     // k sub-col (0,4,8,12)
    const int tx = t & 15, ty = t >> 4;

    float acc[4][4] = {};
    for (int k0 = 0; k0 < K; k0 += 16) {
        float4 av = make_float4(0.f,0.f,0.f,0.f);
        float4 bv = make_float4(0.f,0.f,0.f,0.f);
        if (m0 + lr < M) av = *(const float4*)(A + (size_t)(m0 + lr) * K + k0 + lc);
        if (n0 + lr < N) bv = *(const float4*)(B + (size_t)(n0 + lr) * K + k0 + lc);
        __syncthreads();
        As[lc+0][lr] = av.x; As[lc+1][lr] = av.y; As[lc+2][lr] = av.z; As[lc+3][lr] = av.w;
        Bs[lc+0][lr] = bv.x; Bs[lc+1][lr] = bv.y; Bs[lc+2][lr] = bv.z; Bs[lc+3][lr] = bv.w;
        __syncthreads();
        #pragma unroll
        for (int kk = 0; kk < 16; ++kk) {
            float4 a4 = *(const float4*)&As[kk][ty * 4];
            float4 b4 = *(const float4*)&Bs[kk][tx * 4];
            float af[4] = {a4.x, a4.y, a4.z, a4.w};
            float bf[4] = {b4.x, b4.y, b4.z, b4.w};
            #pragma unroll
            for (int i = 0; i < 4; ++i)
                #pragma unroll
                for (int j = 0; j < 4; ++j)
                    acc[i][j] += af[i] * bf[j];
        }
    }

    const int n = n0 + tx * 4;
    #pragma unroll
    for (int i = 0; i < 4; ++i) {
        const int mi = m0 + ty * 4 + i;
        if (mi >= M) break;
        if (mode == 0) {
            #pragma unroll
            for (int j = 0; j < 4; ++j) {
                if (n + j < N)
                    C[(size_t)mi * ldc + n + j] = acc[i][j] + (bias ? bias[n + j] : 0.f);
            }
        } else {
            float* dst;
            if      (n < 512)  dst = q_ws + (size_t)mi * 512 + n;
            else if (n < 1024) dst = ck   + (size_t)mi * 512 + (n - 512);
            else if (n < 1280) dst = cv   + (size_t)mi * 256 + (n - 1024);
            else if (n < 1312) dst = p_ws + (size_t)mi * 32  + (n - 1280);
            else continue;
            #pragma unroll
            for (int j = 0; j < 4; ++j)
                dst[j] = acc[i][j] + bias[n + j];
        }
    }
}

// Scores + relative-position bias + softmax. One block per (b*H+h, 8-row s tile).
__global__ __launch_bounds__(256)
void attn_scores(const float* __restrict__ q_ws, const float* __restrict__ p_ws,
                 const float* __restrict__ pos_ws,
                 const float* __restrict__ ck_in, const float* __restrict__ ck_new,
                 float* __restrict__ weights)
{
    const int t  = threadIdx.x;
    const int s0 = blockIdx.x * 8;
    const int bh = blockIdx.y;          // b*8 + h
    const int b  = bh >> 3, h = bh & 7;

    __shared__ float  q_s[8][64];       // 2 KB
    __shared__ float4 pos_s[1031];      // 16.5 KB: pos window for this (s-tile,h)
    __shared__ float  s_s[8][1024];     // 32 KB scores
    __shared__ float  red_m[8], red_l[8];

    for (int i = t; i < 8 * 64; i += 256) {
        int si = i >> 6, d = i & 63;
        q_s[si][d] = q_ws[((size_t)(s0 + si) * 16 + b) * 512 + h * 64 + d];
    }
    const int j0 = 504 - s0;            // pos row window start: idx = 7 - si + n
    for (int j = t; j < 1031; j += 256)
        pos_s[j] = *(const float4*)(pos_ws + (size_t)(j0 + j) * 32 + h * 4);
    __syncthreads();

    float4 pv[8];
    #pragma unroll
    for (int si = 0; si < 8; ++si)
        pv[si] = *(const float4*)(p_ws + ((size_t)(s0 + si) * 16 + b) * 32 + h * 4);

    float acc[8][4];
    #pragma unroll
    for (int si = 0; si < 8; ++si)
        #pragma unroll
        for (int j = 0; j < 4; ++j) acc[si][j] = 0.f;

    const float* kbase[4];
    #pragma unroll
    for (int j = 0; j < 4; ++j) {
        int n = t + 256 * j;
        kbase[j] = (n < 512) ? ck_in  + ((size_t)n * 16 + b) * 512 + h * 64
                             : ck_new + ((size_t)(n - 512) * 16 + b) * 512 + h * 64;
    }
    for (int d4 = 0; d4 < 16; ++d4) {
        float4 kv[4];
        #pragma unroll
        for (int j = 0; j < 4; ++j) kv[j] = *(const float4*)(kbase[j] + d4 * 4);
        #pragma unroll
        for (int si = 0; si < 8; ++si) {
            float4 qv = *(const float4*)&q_s[si][d4 * 4];
            #pragma unroll
            for (int j = 0; j < 4; ++j)
                acc[si][j] += qv.x * kv[j].x + qv.y * kv[j].y
                            + qv.z * kv[j].z + qv.w * kv[j].w;
        }
    }
    #pragma unroll
    for (int j = 0; j < 4; ++j) {
        int n = t + 256 * j;
        #pragma unroll
        for (int si = 0; si < 8; ++si) {
            float4 pp = pos_s[7 - si + n];
            s_s[si][n] = acc[si][j] + pv[si].x * pp.x + pv[si].y * pp.y
                                    + pv[si].z * pp.z + pv[si].w * pp.w;
        }
    }
    __syncthreads();

    // softmax: wave w owns rows 2w, 2w+1
    const int wv = t >> 6, lane = t & 63;
    for (int r = wv * 2; r < wv * 2 + 2; ++r) {
        float mx = -1e30f;
        for (int c = lane; c < 1024; c += 64) mx = fmaxf(mx, s_s[r][c]);
        #pragma unroll
        for (int off = 32; off; off >>= 1) mx = fmaxf(mx, __shfl_xor(mx, off));
        float sum = 0.f;
        for (int c = lane; c < 1024; c += 64) sum += expf(s_s[r][c] - mx);
        #pragma unroll
        for (int off = 32; off; off >>= 1) sum += __shfl_xor(sum, off);
        if (lane == 0) { red_m[r] = mx; red_l[r] = 1.0f / sum; }
    }
    __syncthreads();

    const size_t wbase = ((size_t)bh * 512 + s0) * 1024;
    for (int i = t; i < 8 * 1024; i += 256) {
        int r = i >> 10, c = i & 1023;
        weights[wbase + (size_t)r * 1024 + c] = expf(s_s[r][c] - red_m[r]) * red_l[r];
    }
}

// PV: attnout[s,b,h*32+d] = sum_n attn[bh,s,n] * v[n,b,h*32+d]
__global__ __launch_bounds__(256)
void attn_pv(const float* __restrict__ weights,
             const float* __restrict__ cv_in, const float* __restrict__ cv_new,
             float* __restrict__ attnout)
{
    const int t  = threadIdx.x;
    const int s0 = blockIdx.x * 8;
    const int bh = blockIdx.y;
    const int b  = bh >> 3, h = bh & 7;
    const int d  = t & 31, g = t >> 5;        // 8 n-groups of 128
    const size_t wbase = ((size_t)bh * 512 + s0) * 1024;

    float acc[8] = {};
    for (int n4 = g * 128; n4 < g * 128 + 128; n4 += 4) {
        float vv[4];
        #pragma unroll
        for (int u = 0; u < 4; ++u) {
            int n = n4 + u;
            vv[u] = (n < 512) ? cv_in [((size_t)n * 16 + b) * 256 + h * 32 + d]
                              : cv_new[((size_t)(n - 512) * 16 + b) * 256 + h * 32 + d];
        }
        #pragma unroll
        for (int si = 0; si < 8; ++si) {
            float4 aw = *(const float4*)(weights + wbase + (size_t)si * 1024 + n4);
            acc[si] += aw.x * vv[0] + aw.y * vv[1] + aw.z * vv[2] + aw.w * vv[3];
        }
    }
    #pragma unroll
    for (int si = 0; si < 8; ++si) acc[si] += __shfl_xor(acc[si], 32);

    __shared__ float red[4][8][32];
    const int wv = t >> 6;
    if ((t & 32) == 0) {
        #pragma unroll
        for (int si = 0; si < 8; ++si) red[wv][si][d] = acc[si];
    }
    __syncthreads();
    {
        int si = t >> 5, dd = t & 31;
        float s = red[0][si][dd] + red[1][si][dd] + red[2][si][dd] + red[3][si][dd];
        attnout[((size_t)(s0 + si) * 16 + b) * 256 + h * 32 + dd] = s;
    }
}

extern "C" void kernel_launch(void* const* d_in, const int* in_sizes, int n_in,
                              void* d_out, int out_size, void* d_ws, size_t ws_size,
                              hipStream_t stream)
{
    const float* x            = (const float*)d_in[0];
    const float* cached_key   = (const float*)d_in[1];
    const float* cached_val   = (const float*)d_in[2];
    const float* pos_emb      = (const float*)d_in[3];
    const float* in_proj_w    = (const float*)d_in[4];
    const float* in_proj_b    = (const float*)d_in[5];
    const float* linear_pos_w = (const float*)d_in[6];
    const float* out_proj_w   = (const float*)d_in[7];
    const float* out_proj_b   = (const float*)d_in[8];

    float* out     = (float*)d_out;
    float* weights = out + 4194304;          // 128*512*1024
    float* ck_new  = weights + 67108864;     // 512*16*512
    float* cv_new  = ck_new + 4194304;       // 512*16*256

    float* ws      = (float*)d_ws;           // needs 26.5 MB
    float* q_ws    = ws;                     // 8192*512
    float* p_ws    = ws + 4194304;           // 8192*32
    float* pos_ws  = p_ws + 262144;          // 1535*32
    float* attnout = pos_ws + 49120;         // 8192*256

    // 1) in_proj GEMM, split outputs (q | k_new->d_out | v_new->d_out | p)
    gemm_nt<<<dim3(21, 128), 256, 0, stream>>>(x, in_proj_w, in_proj_b,
                                               8192, 1312, 512, 1, nullptr, 0,
                                               q_ws, ck_new, cv_new, p_ws);
    // 2) pos projection
    gemm_nt<<<dim3(1, 24), 256, 0, stream>>>(pos_emb, linear_pos_w, nullptr,
                                             1535, 32, 512, 0, pos_ws, 32,
                                             nullptr, nullptr, nullptr, nullptr);
    // 3) scores (+rel-pos) + softmax -> weights output
    attn_scores<<<dim3(64, 128), 256, 0, stream>>>(q_ws, p_ws, pos_ws,
                                                   cached_key, ck_new, weights);
    // 4) attn @ V
    attn_pv<<<dim3(64, 128), 256, 0, stream>>>(weights, cached_val, cv_new, attnout);
    // 5) out_proj GEMM
    gemm_nt<<<dim3(8, 128), 256, 0, stream>>>(attnout, out_proj_w, out_proj_b,
                                              8192, 512, 256, 0, out, 512,
                                              nullptr, nullptr, nullptr, nullptr);
}

// Round 2
// 752.655 us; speedup vs baseline: 1.4988x; 1.4988x over previous
//
#include <hip/hip_runtime.h>
#include <math.h>

// ---------------------------------------------------------------------------
// Problem constants (S=512, B=16, E=512, A=512, H=8, P=4, L=512)
//   hd=64, vd=32, KV=1024, S2=1535, in_out=1312
// Output layout (floats): out[4194304] | weights[67108864] | ck[4194304] | cv[2097152]
// Workspace (floats): q[4194304] | p[262144] | pos[49120] | attnout[2097152] | kt[8388608]
// ---------------------------------------------------------------------------

// Generic f32 GEMM-NT: C[M,N] = A[M,K] * B[N,K]^T (+bias). mode==1 routes the
// in_proj output columns to q_ws / ck / cv / p_ws (boundaries are tile-aligned).
__global__ __launch_bounds__(256)
void gemm_nt(const float* __restrict__ A, const float* __restrict__ B,
             const float* __restrict__ bias, int M, int N, int K,
             int mode, float* __restrict__ C, int ldc,
             float* __restrict__ q_ws, float* __restrict__ ck,
             float* __restrict__ cv, float* __restrict__ p_ws)
{
    __shared__ float As[16][68];   // transposed tiles, padded (bank-friendly)
    __shared__ float Bs[16][68];
    const int t  = threadIdx.x;
    const int m0 = blockIdx.y * 64, n0 = blockIdx.x * 64;
    const int lr = t >> 2;          // 0..63 tile row
    const int lc = (t & 3) * 4;     // k sub-col (0,4,8,12)
    const int tx = t & 15, ty = t >> 4;

    float acc[4][4] = {};
    for (int k0 = 0; k0 < K; k0 += 16) {
        float4 av = make_float4(0.f,0.f,0.f,0.f);
        float4 bv = make_float4(0.f,0.f,0.f,0.f);
        if (m0 + lr < M) av = *(const float4*)(A + (size_t)(m0 + lr) * K + k0 + lc);
        if (n0 + lr < N) bv = *(const float4*)(B + (size_t)(n0 + lr) * K + k0 + lc);
        __syncthreads();
        As[lc+0][lr] = av.x; As[lc+1][lr] = av.y; As[lc+2][lr] = av.z; As[lc+3][lr] = av.w;
        Bs[lc+0][lr] = bv.x; Bs[lc+1][lr] = bv.y; Bs[lc+2][lr] = bv.z; Bs[lc+3][lr] = bv.w;
        __syncthreads();
        #pragma unroll
        for (int kk = 0; kk < 16; ++kk) {
            float4 a4 = *(const float4*)&As[kk][ty * 4];
            float4 b4 = *(const float4*)&Bs[kk][tx * 4];
            float af[4] = {a4.x, a4.y, a4.z, a4.w};
            float bf[4] = {b4.x, b4.y, b4.z, b4.w};
            #pragma unroll
            for (int i = 0; i < 4; ++i)
                #pragma unroll
                for (int j = 0; j < 4; ++j)
                    acc[i][j] += af[i] * bf[j];
        }
    }

    const int n = n0 + tx * 4;
    #pragma unroll
    for (int i = 0; i < 4; ++i) {
        const int mi = m0 + ty * 4 + i;
        if (mi >= M) break;
        if (mode == 0) {
            #pragma unroll
            for (int j = 0; j < 4; ++j) {
                if (n + j < N)
                    C[(size_t)mi * ldc + n + j] = acc[i][j] + (bias ? bias[n + j] : 0.f);
            }
        } else {
            float* dst;
            if      (n < 512)  dst = q_ws + (size_t)mi * 512 + n;
            else if (n < 1024) dst = ck   + (size_t)mi * 512 + (n - 512);
            else if (n < 1280) dst = cv   + (size_t)mi * 256 + (n - 1024);
            else if (n < 1312) dst = p_ws + (size_t)mi * 32  + (n - 1280);
            else continue;
            #pragma unroll
            for (int j = 0; j < 4; ++j)
                dst[j] = acc[i][j] + bias[n + j];
        }
    }
}

// Build KT[bh][d=64][n=1024] from cached_key ([n][b][A]) + ck_new so that
// attn_scores' K loads are wave-contiguous over n.
__global__ __launch_bounds__(256)
void transpose_k(const float* __restrict__ ck_in, const float* __restrict__ ck_new,
                 float* __restrict__ kt)
{
    const int t  = threadIdx.x;
    const int n0 = blockIdx.x * 64;
    const int bh = blockIdx.y;
    const int b  = bh >> 3, h = bh & 7;

    __shared__ float tile[64][65];   // [d][n_local], padded

    #pragma unroll
    for (int pass = 0; pass < 4; ++pass) {
        const int nl = (t >> 4) + pass * 16;     // local n row
        const int c4 = (t & 15) * 4;             // d sub-col
        const int n  = n0 + nl;
        const float* src = (n < 512)
            ? ck_in  + ((size_t)n * 16 + b) * 512 + h * 64 + c4
            : ck_new + ((size_t)(n - 512) * 16 + b) * 512 + h * 64 + c4;
        float4 v = *(const float4*)src;
        tile[c4 + 0][nl] = v.x; tile[c4 + 1][nl] = v.y;
        tile[c4 + 2][nl] = v.z; tile[c4 + 3][nl] = v.w;
    }
    __syncthreads();
    #pragma unroll
    for (int pass = 0; pass < 4; ++pass) {
        const int d  = (t >> 4) + pass * 16;
        const int n4 = (t & 15) * 4;
        float4 v = make_float4(tile[d][n4], tile[d][n4 + 1],
                               tile[d][n4 + 2], tile[d][n4 + 3]);
        *(float4*)(kt + ((size_t)bh * 64 + d) * 1024 + n0 + n4) = v;
    }
}

__device__ __forceinline__ float wave_max(float v) {
    #pragma unroll
    for (int off = 32; off; off >>= 1) v = fmaxf(v, __shfl_xor(v, off));
    return v;
}
__device__ __forceinline__ float wave_sum(float v) {
    #pragma unroll
    for (int off = 32; off; off >>= 1) v += __shfl_xor(v, off);
    return v;
}

// Scores + rel-pos bias + softmax, scores held in registers.
// Block = (bh, 8-row s tile); thread t owns cols 4t..4t+3.
__global__ __launch_bounds__(256)
void attn_scores(const float* __restrict__ q_ws, const float* __restrict__ p_ws,
                 const float* __restrict__ pos_ws, const float* __restrict__ kt,
                 float* __restrict__ weights)
{
    const int t  = threadIdx.x;
    const int s0 = blockIdx.x * 8;
    const int bh = blockIdx.y;          // b*8 + h
    const int b  = bh >> 3, h = bh & 7;

    __shared__ float  q_s[8][64];       // 2 KB
    __shared__ float4 pos_s[1031];      // 16.5 KB
    __shared__ float  red_m[4][8], red_l[4][8];

    for (int i = t; i < 8 * 64; i += 256) {
        int si = i >> 6, d = i & 63;
        q_s[si][d] = q_ws[((size_t)(s0 + si) * 16 + b) * 512 + h * 64 + d];
    }
    const int j0 = 504 - s0;            // pos row window start: idx = 7 - si + n
    for (int j = t; j < 1031; j += 256)
        pos_s[j] = *(const float4*)(pos_ws + (size_t)(j0 + j) * 32 + h * 4);
    __syncthreads();

    // ---- QK^T: acc[si][u] = q[s0+si] . K[4t+u] ----
    const float* ktb = kt + (size_t)bh * 64 * 1024 + 4 * t;
    float acc[8][4];
    #pragma unroll
    for (int si = 0; si < 8; ++si)
        #pragma unroll
        for (int u = 0; u < 4; ++u) acc[si][u] = 0.f;

    for (int d4 = 0; d4 < 16; ++d4) {
        float4 kv[4];
        #pragma unroll
        for (int dd = 0; dd < 4; ++dd)
            kv[dd] = *(const float4*)(ktb + (size_t)(d4 * 4 + dd) * 1024);
        #pragma unroll
        for (int si = 0; si < 8; ++si) {
            float4 q4 = *(const float4*)&q_s[si][d4 * 4];
            float qf[4] = {q4.x, q4.y, q4.z, q4.w};
            #pragma unroll
            for (int dd = 0; dd < 4; ++dd) {
                acc[si][0] += qf[dd] * kv[dd].x;
                acc[si][1] += qf[dd] * kv[dd].y;
                acc[si][2] += qf[dd] * kv[dd].z;
                acc[si][3] += qf[dd] * kv[dd].w;
            }
        }
    }

    // ---- rel-pos bias ----
    #pragma unroll
    for (int si = 0; si < 8; ++si) {
        float4 pvi = *(const float4*)(p_ws + ((size_t)(s0 + si) * 16 + b) * 32 + h * 4);
        #pragma unroll
        for (int u = 0; u < 4; ++u) {
            float4 pp = pos_s[7 - si + 4 * t + u];
            acc[si][u] += pvi.x * pp.x + pvi.y * pp.y + pvi.z * pp.z + pvi.w * pp.w;
        }
    }

    // ---- block softmax over 1024 cols per row ----
    const int wv = t >> 6, lane = t & 63;
    float m[8];
    #pragma unroll
    for (int si = 0; si < 8; ++si) {
        float v = fmaxf(fmaxf(acc[si][0], acc[si][1]), fmaxf(acc[si][2], acc[si][3]));
        v = wave_max(v);
        if (lane == 0) red_m[wv][si] = v;
    }
    __syncthreads();
    #pragma unroll
    for (int si = 0; si < 8; ++si)
        m[si] = fmaxf(fmaxf(red_m[0][si], red_m[1][si]),
                      fmaxf(red_m[2][si], red_m[3][si]));

    #pragma unroll
    for (int si = 0; si < 8; ++si) {
        float s = 0.f;
        #pragma unroll
        for (int u = 0; u < 4; ++u) {
            acc[si][u] = __expf(acc[si][u] - m[si]);
            s += acc[si][u];
        }
        s = wave_sum(s);
        if (lane == 0) red_l[wv][si] = s;
    }
    __syncthreads();

    const size_t wbase = ((size_t)bh * 512 + s0) * 1024 + 4 * t;
    #pragma unroll
    for (int si = 0; si < 8; ++si) {
        float inv = 1.0f / (red_l[0][si] + red_l[1][si] + red_l[2][si] + red_l[3][si]);
        float4 wv4 = make_float4(acc[si][0] * inv, acc[si][1] * inv,
                                 acc[si][2] * inv, acc[si][3] * inv);
        *(float4*)(weights + wbase + (size_t)si * 1024) = wv4;
    }
}

// PV: attnout[s,b,h*32+d] = sum_n attn[bh,s,n] * v[n,b,h*32+d]
__global__ __launch_bounds__(256)
void attn_pv(const float* __restrict__ weights,
             const float* __restrict__ cv_in, const float* __restrict__ cv_new,
             float* __restrict__ attnout)
{
    const int t  = threadIdx.x;
    const int s0 = blockIdx.x * 8;
    const int bh = blockIdx.y;
    const int b  = bh >> 3, h = bh & 7;
    const int d  = t & 31, g = t >> 5;        // 8 n-groups of 128
    const size_t wbase = ((size_t)bh * 512 + s0) * 1024;

    float acc[8] = {};
    for (int n4 = g * 128; n4 < g * 128 + 128; n4 += 4) {
        float vv[4];
        #pragma unroll
        for (int u = 0; u < 4; ++u) {
            int n = n4 + u;
            vv[u] = (n < 512) ? cv_in [((size_t)n * 16 + b) * 256 + h * 32 + d]
                              : cv_new[((size_t)(n - 512) * 16 + b) * 256 + h * 32 + d];
        }
        #pragma unroll
        for (int si = 0; si < 8; ++si) {
            float4 aw = *(const float4*)(weights + wbase + (size_t)si * 1024 + n4);
            acc[si] += aw.x * vv[0] + aw.y * vv[1] + aw.z * vv[2] + aw.w * vv[3];
        }
    }
    #pragma unroll
    for (int si = 0; si < 8; ++si) acc[si] += __shfl_xor(acc[si], 32);

    __shared__ float red[4][8][32];
    const int wv = t >> 6;
    if ((t & 32) == 0) {
        #pragma unroll
        for (int si = 0; si < 8; ++si) red[wv][si][d] = acc[si];
    }
    __syncthreads();
    {
        int si = t >> 5, dd = t & 31;
        float s = red[0][si][dd] + red[1][si][dd] + red[2][si][dd] + red[3][si][dd];
        attnout[((size_t)(s0 + si) * 16 + b) * 256 + h * 32 + dd] = s;
    }
}

extern "C" void kernel_launch(void* const* d_in, const int* in_sizes, int n_in,
                              void* d_out, int out_size, void* d_ws, size_t ws_size,
                              hipStream_t stream)
{
    const float* x            = (const float*)d_in[0];
    const float* cached_key   = (const float*)d_in[1];
    const float* cached_val   = (const float*)d_in[2];
    const float* pos_emb      = (const float*)d_in[3];
    const float* in_proj_w    = (const float*)d_in[4];
    const float* in_proj_b    = (const float*)d_in[5];
    const float* linear_pos_w = (const float*)d_in[6];
    const float* out_proj_w   = (const float*)d_in[7];
    const float* out_proj_b   = (const float*)d_in[8];

    float* out     = (float*)d_out;
    float* weights = out + 4194304;          // 128*512*1024
    float* ck_new  = weights + 67108864;     // 512*16*512
    float* cv_new  = ck_new + 4194304;       // 512*16*256

    float* ws      = (float*)d_ws;           // needs ~60 MB
    float* q_ws    = ws;                     // 8192*512
    float* p_ws    = ws + 4194304;           // 8192*32
    float* pos_ws  = p_ws + 262144;          // 1535*32
    float* attnout = pos_ws + 49120;         // 8192*256
    float* kt_ws   = attnout + 2097152;      // 128*64*1024

    // 1) in_proj GEMM, split outputs (q | k_new->d_out | v_new->d_out | p)
    gemm_nt<<<dim3(21, 128), 256, 0, stream>>>(x, in_proj_w, in_proj_b,
                                               8192, 1312, 512, 1, nullptr, 0,
                                               q_ws, ck_new, cv_new, p_ws);
    // 2) pos projection
    gemm_nt<<<dim3(1, 24), 256, 0, stream>>>(pos_emb, linear_pos_w, nullptr,
                                             1535, 32, 512, 0, pos_ws, 32,
                                             nullptr, nullptr, nullptr, nullptr);
    // 3) K -> KT[bh][d][n]
    transpose_k<<<dim3(16, 128), 256, 0, stream>>>(cached_key, ck_new, kt_ws);
    // 4) scores (+rel-pos) + softmax -> weights output
    attn_scores<<<dim3(64, 128), 256, 0, stream>>>(q_ws, p_ws, pos_ws, kt_ws, weights);
    // 5) attn @ V
    attn_pv<<<dim3(64, 128), 256, 0, stream>>>(weights, cached_val, cv_new, attnout);
    // 6) out_proj GEMM
    gemm_nt<<<dim3(8, 128), 256, 0, stream>>>(attnout, out_proj_w, out_proj_b,
                                              8192, 512, 256, 0, out, 512,
                                              nullptr, nullptr, nullptr, nullptr);
}